// Round 10
// baseline (265.662 us; speedup 1.0000x reference)
//
#include <hip/hip_runtime.h>

typedef unsigned short u16;
typedef unsigned int   u32;
typedef __bf16 bf16x8 __attribute__((ext_vector_type(8)));
typedef float  f32x4  __attribute__((ext_vector_type(4)));
typedef _Float16 h2 __attribute__((ext_vector_type(2)));
typedef u32 u32x4 __attribute__((ext_vector_type(4)));   // native vec for nontemporal builtins

#define M_ROWS 50000
#define M_PAD  50176    // 196 x 256
#define M_TILES 196     // 256-row tiles
#define N_REAL 1368     // 3 br * 3 tap * 152
#define N_PAD  1536
#define N_TILES64 22    // 64-col tiles actually used (cols 0..1407)
#define K_DIM  300
#define K_PAD  320
#define KT     10       // K-chunks of 32
#define TROW   1408     // u16 elements per T row (2816 B)
#define SEG    152      // (br,tap) segment width; br stride 456
#define YCOL   152      // LDS ybuf row width (19 groups * 8)
#define NBLKA  1960     // build_A blocks (196 tiles x 10 kt)
#define NBLKB  1920     // build_B blocks

#define GLDS(gp, lp) __builtin_amdgcn_global_load_lds( \
    (const __attribute__((address_space(1))) void*)(gp), \
    (__attribute__((address_space(3))) void*)(lp), 16, 0, 0)

static __device__ __forceinline__ u16 f2bf(float x){
  union { float f; u32 u; } a; a.f = x;
  u32 r = a.u + 0x7fffu + ((a.u >> 16) & 1u);   // RNE
  return (u16)(r >> 16);
}
static __device__ __forceinline__ u16 f2h(float x){
  _Float16 h = (_Float16)x;
  u16 r; __builtin_memcpy(&r, &h, 2); return r;
}
static __device__ __forceinline__ float h2f(u16 v){
  _Float16 h; __builtin_memcpy(&h, &v, 2); return (float)h;
}

// ---- DPP wave reductions via raw asm (6 VALU inst; s_nop covers DPP wait states).
static __device__ __forceinline__ float wsum63(float x){
  asm volatile(
    "s_nop 1\n\t"
    "v_add_f32 %0, %0, %0 row_shr:1 bound_ctrl:0\n\t"
    "s_nop 1\n\t"
    "v_add_f32 %0, %0, %0 row_shr:2 bound_ctrl:0\n\t"
    "s_nop 1\n\t"
    "v_add_f32 %0, %0, %0 row_shr:4 bound_ctrl:0\n\t"
    "s_nop 1\n\t"
    "v_add_f32 %0, %0, %0 row_shr:8 bound_ctrl:0\n\t"
    "s_nop 1\n\t"
    "v_add_f32 %0, %0, %0 row_bcast:15 row_mask:0xa\n\t"
    "s_nop 1\n\t"
    "v_add_f32 %0, %0, %0 row_bcast:31 row_mask:0xc\n\t"
    "s_nop 1"
    : "+v"(x));
  return x;
}
static __device__ __forceinline__ float wmax63(float x){
  asm volatile(
    "s_nop 1\n\t"
    "v_max_f32 %0, %0, %0 row_shr:1\n\t"
    "s_nop 1\n\t"
    "v_max_f32 %0, %0, %0 row_shr:2\n\t"
    "s_nop 1\n\t"
    "v_max_f32 %0, %0, %0 row_shr:4\n\t"
    "s_nop 1\n\t"
    "v_max_f32 %0, %0, %0 row_shr:8\n\t"
    "s_nop 1\n\t"
    "v_max_f32 %0, %0, %0 row_bcast:15 row_mask:0xa\n\t"
    "s_nop 1\n\t"
    "v_max_f32 %0, %0, %0 row_bcast:31 row_mask:0xc\n\t"
    "s_nop 1"
    : "+v"(x));
  return x;
}
static __device__ __forceinline__ float rdl63(float x){
  union { float f; int i; } a; a.f = x;
  union { int i; float f; } r; r.i = __builtin_amdgcn_readlane(a.i, 63);
  return r.f;
}

// ---------------- K1: merged build_A (LDS-staged) + build_B -----------------------
__global__ __launch_bounds__(256) void build_AB(const float* __restrict__ emb,
                                                const float* __restrict__ w1,
                                                const float* __restrict__ w2,
                                                const float* __restrict__ w3,
                                                u16* __restrict__ A, u16* __restrict__ B){
  __shared__ __align__(16) u16 st[8192];
  const int blk = blockIdx.x;
  const int tid = threadIdx.x;
  if (blk < NBLKA){
    // ---- build_A path: one block per (tile, kt) 8192-u16 sub-block ----
    const int tile = blk / KT, kt = blk % KT;
    const int m0 = tile * 256, k0 = kt * 32;
    #pragma unroll
    for (int u = 0; u < 8; ++u){
      int i = tid + u * 256;          // 0..2047
      int r = i >> 3, c = i & 7;      // row 0..255, float4-chunk 0..7
      int m = m0 + r, k = k0 + c * 4;
      float4 v = (float4){0.f, 0.f, 0.f, 0.f};
      if (m < M_ROWS && k < K_DIM)
        v = *(const float4*)(emb + (size_t)m * K_DIM + k);
      int dst = (r >> 4) * 512 + (c >> 1) * 128 + (r & 15) * 8 + (c & 1) * 4;
      union { u32 d[2]; u16 s[4]; } w;
      w.s[0] = f2bf(v.x); w.s[1] = f2bf(v.y); w.s[2] = f2bf(v.z); w.s[3] = f2bf(v.w);
      *(uint2*)(st + dst) = *(const uint2*)w.d;
    }
    __syncthreads();
    u16* out = A + ((size_t)tile * KT + kt) * 8192;
    #pragma unroll
    for (int q = 0; q < 4; ++q){
      int o = tid * 8 + q * 2048;
      *(uint4*)(out + o) = *(const uint4*)(st + o);
    }
  } else {
    // ---- build_B path ----
    int t = (blk - NBLKA) * 256 + tid;
    if (t >= N_PAD * K_PAD) return;
    int n = t / K_PAD, k = t % K_PAD;
    float x = 0.f;
    if (n < N_REAL && k < K_DIM){
      int br = n / 456, rem = n % 456, tap = rem / 152, f = rem % 152;
      if (f < 150){
        const float* w = (br == 0) ? w1 : ((br == 1) ? w2 : w3);
        x = w[(tap * K_DIM + k) * 150 + f];
      }
    }
    int tn = n >> 7, nl = n & 127, nb = nl >> 4, col = nl & 15;
    int kt = k >> 5, kl = k & 31, kg = kl >> 3, k8 = kl & 7;
    B[((size_t)tn * KT + kt) * 4096 + nb * 512 + kg * 128 + col * 8 + k8] = f2bf(x);
  }
}

// ---------------- K2: T = A x B^T  (128x64 block, BK=64 x 5 stages, 5 blk/CU) -----
// R6 structure (best measured) + ONE change: nontemporal T stores. T is
// write-once data; nt skips L2 allocation so dirty T lines stop competing
// with A/B reuse in L2 for the whole kernel.
__global__ __launch_bounds__(256, 5) void gemm_k(const u16* __restrict__ A, const u16* __restrict__ B,
                                                 u16* __restrict__ T){
  __shared__ __align__(16) u16 lds[12288];  // 24.6 KB: lA 8192 u16 | lB 4096 u16
  const int flat = blockIdx.x;
  const int xcd = flat & 7, ord = flat >> 3;
  const int wg = xcd * 1078 + ord;              // 8624 = 8*1078 exact -> bijective
  const int tn = wg % 22, tM = wg / 22;         // tM in 0..391 (128-row tiles)
  const int t256 = tM >> 1, hM = tM & 1;        // half of the 256-row A macro-tile
  const int tn128 = tn >> 1, h64 = tn & 1;      // half of the 128-col B macro-tile
  const int tid = threadIdx.x, wave = tid >> 6, lane = tid & 63;
  const int wm = wave >> 1, wn = wave & 1;      // 2x2 wave grid, wave tile 64x32
  f32x4 acc[4][2];
  #pragma unroll
  for (int i = 0; i < 4; ++i)
    #pragma unroll
    for (int j = 0; j < 2; ++j) acc[i][j] = (f32x4){0.f, 0.f, 0.f, 0.f};
  const u16* Ab = A + ((size_t)t256 * KT) * 8192 + hM * 4096;  // our 128-row half
  const u16* Bb = B + ((size_t)tn128 * KT) * 4096 + h64 * 2048; // our 64-col half
  #pragma unroll
  for (int s = 0; s < 5; ++s){
    __syncthreads();   // WAR: all waves done reading previous stage
    // A chunks kt=2s, 2s+1 (4096 u16 each, non-contiguous: +0 and +8192)
    GLDS(Ab + s * 16384 + tid * 8,               lds + tid * 8);
    GLDS(Ab + s * 16384 + 2048 + tid * 8,        lds + 2048 + tid * 8);
    GLDS(Ab + s * 16384 + 8192 + tid * 8,        lds + 4096 + tid * 8);
    GLDS(Ab + s * 16384 + 8192 + 2048 + tid * 8, lds + 6144 + tid * 8);
    // B chunks kt=2s, 2s+1 (2048 u16 each)
    GLDS(Bb + s * 8192 + tid * 8,                lds + 8192 + tid * 8);
    GLDS(Bb + s * 8192 + 4096 + tid * 8,         lds + 10240 + tid * 8);
    __syncthreads();   // implies vmcnt(0): tile landed for all waves
    #pragma unroll
    for (int kk = 0; kk < 2; ++kk){
      const bf16x8* A8 = (const bf16x8*)(lds + kk * 4096);
      const bf16x8* B8 = (const bf16x8*)(lds + 8192 + kk * 2048);
      bf16x8 av[4], bv[2];
      #pragma unroll
      for (int i = 0; i < 4; ++i) av[i] = A8[(wm * 4 + i) * 64 + lane];
      #pragma unroll
      for (int j = 0; j < 2; ++j) bv[j] = B8[(wn * 2 + j) * 64 + lane];
      #pragma unroll
      for (int i = 0; i < 4; ++i)
        #pragma unroll
        for (int j = 0; j < 2; ++j)
          acc[i][j] = __builtin_amdgcn_mfma_f32_16x16x32_bf16(av[i], bv[j], acc[i][j], 0, 0, 0);
    }
  }
  // epilogue: per 64-row half, stage f16 tile in LDS (stride 72), nt stores
  const int r0 = (lane >> 4) * 4, c0 = lane & 15;   // C/D: col=lane&15, row=(lane>>4)*4+reg
  const int row = tid >> 2, q = tid & 3;
  #pragma unroll
  for (int h = 0; h < 2; ++h){
    __syncthreads();
    if (wm == h){
      #pragma unroll
      for (int i = 0; i < 4; ++i){
        #pragma unroll
        for (int j = 0; j < 2; ++j){
          int col = wn * 32 + j * 16 + c0;
          #pragma unroll
          for (int r = 0; r < 4; ++r)
            lds[(i * 16 + r0 + r) * 72 + col] = f2h(acc[i][j][r]);
        }
      }
    }
    __syncthreads();
    int m = tM * 128 + h * 64 + row;
    if (m < M_ROWS){
      const u16* src = lds + row * 72 + q * 16;
      u16* dst = T + (size_t)m * TROW + tn * 64 + q * 16;
      __builtin_nontemporal_store(*(const u32x4*)(src),     (u32x4*)(dst));
      __builtin_nontemporal_store(*(const u32x4*)(src + 8), (u32x4*)(dst + 8));
    }
  }
}

// ---------------- K3: per-title encoder (512 thr, MLP-staged gather) --------------
__global__ __launch_bounds__(512, 4) void encode_k(
    const int* __restrict__ cand, const int* __restrict__ clk,
    const u16* __restrict__ T,
    const float* __restrict__ b1, const float* __restrict__ b2, const float* __restrict__ b3,
    const float* __restrict__ lng, const float* __restrict__ lnb,
    const float* __restrict__ ql, const float* __restrict__ qw,
    float* __restrict__ rc, float* __restrict__ rh){
  __shared__ __align__(16) u16 ybuf[90][YCOL];   // summed f16 y (27.4 KB)
  __shared__ float tl[32];                        // logits, then normalized ww
  __shared__ float pbuf[8][YCOL];
  __shared__ u32 wordoff[32];
  const int t = blockIdx.x;
  const int tid = threadIdx.x, wave = tid >> 6, lane = tid & 63;
  const int* wp; float* outp;
  if (t < 320){ wp = cand + t * 30;                outp = rc + t * 150; }
  else        { wp = clk + (size_t)(t - 320) * 30; outp = rh + (size_t)(t - 320) * 150; }
  if (tid < 30) wordoff[tid] = (u32)wp[tid] * (u32)TROW;
  __syncthreads();
  const float invs = 0.057735026918962576f;  // 1/sqrt(300)
  const int f0 = lane, f1 = lane + 64, f2 = lane + 128;
  const bool has2 = (f2 < 150);

  // ---- phase 0: gather with 12 loads in flight (T14 issue-early / combine-late).
  uint4 rv[12]; bool vm[12]; int pA[4], fgA[4]; bool ivA[4];
  #pragma unroll
  for (int it = 0; it < 4; ++it){
    const int item = tid + it * 512;
    const bool iv = item < 1710;
    const int p = item / 19, fg = item - p * 19;    // p = l*3+br
    pA[it] = p; fgA[it] = fg; ivA[it] = iv;
    const int l = p / 3, br = p - l * 3, dil = br + 1;
    #pragma unroll
    for (int tap = 0; tap < 3; ++tap){
      const int ls = l + (tap - 1) * dil;
      const int lsc = ls < 0 ? 0 : (ls > 29 ? 29 : ls);
      vm[it * 3 + tap] = iv && (ls >= 0) && (ls < 30);
      rv[it * 3 + tap] = *(const uint4*)(T + wordoff[lsc] + br * 456 + tap * SEG + fg * 8);
    }
  }
  #pragma unroll
  for (int it = 0; it < 4; ++it){
    if (ivA[it]){
      union { uint4 q; h2 h[4]; } s, va, vb, vc;
      const uint4 z4 = (uint4){0u, 0u, 0u, 0u};
      va.q = vm[it * 3]     ? rv[it * 3]     : z4;
      vb.q = vm[it * 3 + 1] ? rv[it * 3 + 1] : z4;
      vc.q = vm[it * 3 + 2] ? rv[it * 3 + 2] : z4;
      #pragma unroll
      for (int i = 0; i < 4; ++i) s.h[i] = va.h[i] + vb.h[i] + vc.h[i];   // v_pk_add_f16
      *(uint4*)&ybuf[pA[it]][fgA[it] * 8] = s.q;
    }
  }

  // preload per-lane params (uniform across words)
  float qlv0 = ql[f0], qlv1 = ql[f1], qlv2 = has2 ? ql[f2] : 0.f;
  float qwv0 = qw[f0], qwv1 = qw[f1], qwv2 = has2 ? qw[f2] : 0.f;
  float lg0 = lng[f0], lg1 = lng[f1], lg2 = has2 ? lng[f2] : 0.f;
  float lb0 = lnb[f0], lb1 = lnb[f1], lb2 = has2 ? lnb[f2] : 0.f;
  float bs[3][3];
  {
    const float* bl[3] = {b1, b2, b3};
    #pragma unroll
    for (int br = 0; br < 3; ++br){
      bs[br][0] = bl[br][f0]; bs[br][1] = bl[br][f1]; bs[br][2] = has2 ? bl[br][f2] : 0.f;
    }
  }
  __syncthreads();

  // ---- phase 1: word-major LN + level-attn (static 4-iter unroll, asm-DPP) ----
  float at0[4], at1[4], at2[4];
  #pragma unroll
  for (int q = 0; q < 4; ++q){
    const int l = wave + q * 8;
    at0[q] = 0.f; at1[q] = 0.f; at2[q] = 0.f;
    if (l < 30){
      float dr[3][3]; float lvl[3];
      #pragma unroll
      for (int br = 0; br < 3; ++br){
        int p = l * 3 + br;
        float y0 = h2f(ybuf[p][f0]) + bs[br][0];
        float y1 = h2f(ybuf[p][f1]) + bs[br][1];
        float y2 = has2 ? (h2f(ybuf[p][f2]) + bs[br][2]) : 0.f;
        float s  = y0 + y1 + y2;
        float ss = y0 * y0 + y1 * y1 + y2 * y2;
        float st = wsum63(s), sst = wsum63(ss);
        float mean = rdl63(st) * (1.f / 150.f);
        float var  = rdl63(sst) * (1.f / 150.f) - mean * mean;
        float rstd = rsqrtf(var + 1e-5f);
        float d0 = fmaxf((y0 - mean) * rstd * lg0 + lb0, 0.f);
        float d1 = fmaxf((y1 - mean) * rstd * lg1 + lb1, 0.f);
        float d2 = has2 ? fmaxf((y2 - mean) * rstd * lg2 + lb2, 0.f) : 0.f;
        dr[br][0] = d0; dr[br][1] = d1; dr[br][2] = d2;
        float dot = qlv0 * d0 + qlv1 * d1 + qlv2 * d2;
        lvl[br] = rdl63(wsum63(dot)) * invs;
      }
      // wave-local level softmax
      float mx = fmaxf(lvl[0], fmaxf(lvl[1], lvl[2]));
      float e0 = __expf(lvl[0] - mx), e1 = __expf(lvl[1] - mx), e2 = __expf(lvl[2] - mx);
      float inv = 1.f / (e0 + e1 + e2);
      float w0 = e0 * inv, w1v = e1 * inv, w2v = e2 * inv;
      float a0 = w0 * dr[0][0] + w1v * dr[1][0] + w2v * dr[2][0];
      float a1 = w0 * dr[0][1] + w1v * dr[1][1] + w2v * dr[2][1];
      float a2 = w0 * dr[0][2] + w1v * dr[1][2] + w2v * dr[2][2];
      float dot = qwv0 * a0 + qwv1 * a1 + qwv2 * a2;
      float tw = wsum63(dot);
      if (lane == 63) tl[l] = tw * invs;
      at0[q] = a0; at1[q] = a1; at2[q] = a2;
    }
  }
  __syncthreads();

  // ---- phase 2a: word softmax ONCE (wave 0), normalized weights -> tl ----
  if (wave == 0){
    float v = (lane < 30) ? tl[lane] : -1e30f;
    float mx = rdl63(wmax63(v));
    float e = (lane < 30) ? __expf(v - mx) : 0.f;
    float den = rdl63(wsum63(e));
    if (lane < 30) tl[lane] = e / den;
  }
  __syncthreads();

  // ---- phase 2b: weighted combine + per-wave partials (static unroll) ----
  float p0 = 0.f, p1 = 0.f, p2 = 0.f;
  #pragma unroll
  for (int q = 0; q < 4; ++q){
    const int l = wave + q * 8;
    if (l < 30){
      float wwv = tl[l];
      p0 += wwv * at0[q]; p1 += wwv * at1[q]; p2 += wwv * at2[q];
    }
  }
  pbuf[wave][lane] = p0;
  pbuf[wave][lane + 64] = p1;
  if (has2) pbuf[wave][lane + 128] = p2;
  __syncthreads();
  if (tid < 150){
    float acc = 0.f;
    #pragma unroll
    for (int w = 0; w < 8; ++w) acc += pbuf[w][tid];
    outp[tid] = acc;
  }
}

// ---------------- K4: scores -> logits -> log_softmax (LDS-staged) ----------------
__global__ __launch_bounds__(256) void final_k(const float* __restrict__ rc, const float* __restrict__ rh,
                                               const float* __restrict__ lw, const float* __restrict__ lb,
                                               float* __restrict__ out){
  __shared__ float Cl[750];
  __shared__ float Hl[7500];
  __shared__ float sc[5][52];
  __shared__ float lg[5];
  const int b = blockIdx.x, tid = threadIdx.x;
  const float* C = rc + b * 750;
  const float* H = rh + (size_t)b * 7500;
  for (int i = tid; i < 750; i += 256) Cl[i] = C[i];
  for (int i = tid; i < 7500; i += 256) Hl[i] = H[i];
  __syncthreads();
  if (tid < 250){
    int c = tid / 50, h = tid % 50;
    float s = 0.f;
    #pragma unroll 10
    for (int k = 0; k < 150; ++k) s += Cl[c * 150 + k] * Hl[h * 150 + k];
    sc[c][h] = s;
  }
  __syncthreads();
  if (tid < 5){
    float s = lb[0];
    for (int h = 0; h < 50; ++h) s += sc[tid][h] * lw[h];
    lg[tid] = s;
  }
  __syncthreads();
  if (tid < 5){
    float mx = fmaxf(fmaxf(fmaxf(lg[0], lg[1]), fmaxf(lg[2], lg[3])), lg[4]);
    float den = 0.f;
    for (int c = 0; c < 5; ++c) den += expf(lg[c] - mx);
    out[b * 5 + tid] = lg[tid] - mx - logf(den);
  }
}

extern "C" void kernel_launch(void* const* d_in, const int* in_sizes, int n_in,
                              void* d_out, int out_size, void* d_ws, size_t ws_size,
                              hipStream_t stream){
  const int*   cand = (const int*)d_in[0];
  const int*   clk  = (const int*)d_in[1];
  const float* emb  = (const float*)d_in[2];
  const float* w1   = (const float*)d_in[3];
  const float* b1   = (const float*)d_in[4];
  const float* w2   = (const float*)d_in[5];
  const float* b2   = (const float*)d_in[6];
  const float* w3   = (const float*)d_in[7];
  const float* b3   = (const float*)d_in[8];
  const float* lng  = (const float*)d_in[9];
  const float* lnb  = (const float*)d_in[10];
  const float* ql   = (const float*)d_in[11];
  const float* qw   = (const float*)d_in[12];
  const float* lw   = (const float*)d_in[13];
  const float* lb   = (const float*)d_in[14];
  float* out = (float*)d_out;

  char* ws = (char*)d_ws;
  const size_t szA = (size_t)M_TILES * KT * 16384;  // 32,112,640 B
  const size_t szB = (size_t)12 * KT * 8192;        //     983,040 B
  const size_t szT = (size_t)M_ROWS * TROW * 2;     // 140,800,000 B
  u16*   A  = (u16*)ws;
  u16*   B  = (u16*)(ws + szA);
  u16*   T  = (u16*)(ws + szA + szB);
  float* rc = (float*)(ws + szA + szB + szT);
  float* rh = rc + 320 * 150;

  build_AB<<<NBLKA + NBLKB, 256, 0, stream>>>(emb, w1, w2, w3, A, B);
  gemm_k<<<dim3(392 * N_TILES64), 256, 0, stream>>>(A, B, T);
  encode_k<<<3520, 512, 0, stream>>>(cand, clk, T, b1, b2, b3, lng, lnb, ql, qw, rc, rh);
  final_k<<<64, 256, 0, stream>>>(rc, rh, lw, lb, out);
}

// Round 11
// 248.670 us; speedup vs baseline: 1.0683x; 1.0683x over previous
//
#include <hip/hip_runtime.h>

typedef unsigned short u16;
typedef unsigned int   u32;
typedef __bf16 bf16x8 __attribute__((ext_vector_type(8)));
typedef float  f32x4  __attribute__((ext_vector_type(4)));
typedef _Float16 h2 __attribute__((ext_vector_type(2)));

#define M_ROWS 50000
#define M_PAD  50176    // 196 x 256
#define M_TILES 196     // 256-row tiles
#define N_REAL 1368     // 3 br * 3 tap * 152
#define N_PAD  1536
#define N_TILES64 22    // 64-col tiles actually used (cols 0..1407)
#define K_DIM  300
#define K_PAD  320
#define KT     10       // K-chunks of 32
#define TROW   1408     // u16 elements per T row (2816 B)
#define SEG    152      // (br,tap) segment width; br stride 456
#define YCOL   152      // LDS ybuf row width (19 groups * 8)
#define NBLKA  1960     // build_A blocks (196 tiles x 10 kt)
#define NBLKB  1920     // build_B blocks

#define GLDS(gp, lp) __builtin_amdgcn_global_load_lds( \
    (const __attribute__((address_space(1))) void*)(gp), \
    (__attribute__((address_space(3))) void*)(lp), 16, 0, 0)

static __device__ __forceinline__ u16 f2bf(float x){
  union { float f; u32 u; } a; a.f = x;
  u32 r = a.u + 0x7fffu + ((a.u >> 16) & 1u);   // RNE
  return (u16)(r >> 16);
}
static __device__ __forceinline__ u16 f2h(float x){
  _Float16 h = (_Float16)x;
  u16 r; __builtin_memcpy(&r, &h, 2); return r;
}
static __device__ __forceinline__ float h2f(u16 v){
  _Float16 h; __builtin_memcpy(&h, &v, 2); return (float)h;
}

// ---- DPP wave reductions via raw asm (6 VALU inst; s_nop covers DPP wait states).
static __device__ __forceinline__ float wsum63(float x){
  asm volatile(
    "s_nop 1\n\t"
    "v_add_f32 %0, %0, %0 row_shr:1 bound_ctrl:0\n\t"
    "s_nop 1\n\t"
    "v_add_f32 %0, %0, %0 row_shr:2 bound_ctrl:0\n\t"
    "s_nop 1\n\t"
    "v_add_f32 %0, %0, %0 row_shr:4 bound_ctrl:0\n\t"
    "s_nop 1\n\t"
    "v_add_f32 %0, %0, %0 row_shr:8 bound_ctrl:0\n\t"
    "s_nop 1\n\t"
    "v_add_f32 %0, %0, %0 row_bcast:15 row_mask:0xa\n\t"
    "s_nop 1\n\t"
    "v_add_f32 %0, %0, %0 row_bcast:31 row_mask:0xc\n\t"
    "s_nop 1"
    : "+v"(x));
  return x;
}
static __device__ __forceinline__ float wmax63(float x){
  asm volatile(
    "s_nop 1\n\t"
    "v_max_f32 %0, %0, %0 row_shr:1\n\t"
    "s_nop 1\n\t"
    "v_max_f32 %0, %0, %0 row_shr:2\n\t"
    "s_nop 1\n\t"
    "v_max_f32 %0, %0, %0 row_shr:4\n\t"
    "s_nop 1\n\t"
    "v_max_f32 %0, %0, %0 row_shr:8\n\t"
    "s_nop 1\n\t"
    "v_max_f32 %0, %0, %0 row_bcast:15 row_mask:0xa\n\t"
    "s_nop 1\n\t"
    "v_max_f32 %0, %0, %0 row_bcast:31 row_mask:0xc\n\t"
    "s_nop 1"
    : "+v"(x));
  return x;
}
static __device__ __forceinline__ float rdl63(float x){
  union { float f; int i; } a; a.f = x;
  union { int i; float f; } r; r.i = __builtin_amdgcn_readlane(a.i, 63);
  return r.f;
}

// ---------------- K1: merged build_A (LDS-staged) + build_B -----------------------
__global__ __launch_bounds__(256) void build_AB(const float* __restrict__ emb,
                                                const float* __restrict__ w1,
                                                const float* __restrict__ w2,
                                                const float* __restrict__ w3,
                                                u16* __restrict__ A, u16* __restrict__ B){
  __shared__ __align__(16) u16 st[8192];
  const int blk = blockIdx.x;
  const int tid = threadIdx.x;
  if (blk < NBLKA){
    // ---- build_A path: one block per (tile, kt) 8192-u16 sub-block ----
    const int tile = blk / KT, kt = blk % KT;
    const int m0 = tile * 256, k0 = kt * 32;
    #pragma unroll
    for (int u = 0; u < 8; ++u){
      int i = tid + u * 256;          // 0..2047
      int r = i >> 3, c = i & 7;      // row 0..255, float4-chunk 0..7
      int m = m0 + r, k = k0 + c * 4;
      float4 v = (float4){0.f, 0.f, 0.f, 0.f};
      if (m < M_ROWS && k < K_DIM)
        v = *(const float4*)(emb + (size_t)m * K_DIM + k);
      int dst = (r >> 4) * 512 + (c >> 1) * 128 + (r & 15) * 8 + (c & 1) * 4;
      union { u32 d[2]; u16 s[4]; } w;
      w.s[0] = f2bf(v.x); w.s[1] = f2bf(v.y); w.s[2] = f2bf(v.z); w.s[3] = f2bf(v.w);
      *(uint2*)(st + dst) = *(const uint2*)w.d;
    }
    __syncthreads();
    u16* out = A + ((size_t)tile * KT + kt) * 8192;
    #pragma unroll
    for (int q = 0; q < 4; ++q){
      int o = tid * 8 + q * 2048;
      *(uint4*)(out + o) = *(const uint4*)(st + o);
    }
  } else {
    // ---- build_B path ----
    int t = (blk - NBLKA) * 256 + tid;
    if (t >= N_PAD * K_PAD) return;
    int n = t / K_PAD, k = t % K_PAD;
    float x = 0.f;
    if (n < N_REAL && k < K_DIM){
      int br = n / 456, rem = n % 456, tap = rem / 152, f = rem % 152;
      if (f < 150){
        const float* w = (br == 0) ? w1 : ((br == 1) ? w2 : w3);
        x = w[(tap * K_DIM + k) * 150 + f];
      }
    }
    int tn = n >> 7, nl = n & 127, nb = nl >> 4, col = nl & 15;
    int kt = k >> 5, kl = k & 31, kg = kl >> 3, k8 = kl & 7;
    B[((size_t)tn * KT + kt) * 4096 + nb * 512 + kg * 128 + col * 8 + k8] = f2bf(x);
  }
}

// ---------------- K2: T = A x B^T  (128x64 block, BK=32, 8 blocks/CU) -------------
// R5 structure (best-measured family, 68 us) with the occupancy hint raised to
// 8 blocks/CU: VGPR 32 (<=64 -> 8 waves/SIMD ok), LDS 12.3 KB (x8 = 98 KB ok).
// Tests whether the launch_bounds hint was the residency cap (MLP theory).
// Plain uint4 stores (R10: nontemporal stores caused 1.79x write amplification).
__global__ __launch_bounds__(256, 8) void gemm_k(const u16* __restrict__ A, const u16* __restrict__ B,
                                                 u16* __restrict__ T){
  __shared__ __align__(16) u16 lds[6144];  // 12.3 KB: lA 4096 u16 | lB 2048 u16; epilogue 64x72
  const int flat = blockIdx.x;
  const int xcd = flat & 7, ord = flat >> 3;
  const int wg = xcd * 1078 + ord;              // 8624 = 8*1078 exact -> bijective
  const int tn = wg % 22, tM = wg / 22;         // tM in 0..391 (128-row tiles)
  const int t256 = tM >> 1, hM = tM & 1;        // half of the 256-row A macro-tile
  const int tn128 = tn >> 1, h64 = tn & 1;      // half of the 128-col B macro-tile
  const int tid = threadIdx.x, wave = tid >> 6, lane = tid & 63;
  const int wm = wave >> 1, wn = wave & 1;      // 2x2 wave grid, wave tile 64x32
  f32x4 acc[4][2];
  #pragma unroll
  for (int i = 0; i < 4; ++i)
    #pragma unroll
    for (int j = 0; j < 2; ++j) acc[i][j] = (f32x4){0.f, 0.f, 0.f, 0.f};
  const u16* Ab = A + ((size_t)t256 * KT) * 8192 + hM * 4096;
  const u16* Bb = B + ((size_t)tn128 * KT) * 4096 + h64 * 2048;
  #pragma unroll
  for (int s = 0; s < 10; ++s){
    __syncthreads();   // WAR: all waves done reading previous stage
    GLDS(Ab + s * 8192 + tid * 8,        lds + tid * 8);
    GLDS(Ab + s * 8192 + 2048 + tid * 8, lds + 2048 + tid * 8);
    GLDS(Bb + s * 4096 + tid * 8,        lds + 4096 + tid * 8);
    __syncthreads();   // implies vmcnt(0): tile landed for all waves
    const bf16x8* A8 = (const bf16x8*)lds;
    const bf16x8* B8 = (const bf16x8*)(lds + 4096);
    bf16x8 av[4], bv[2];
    #pragma unroll
    for (int i = 0; i < 4; ++i) av[i] = A8[(wm * 4 + i) * 64 + lane];
    #pragma unroll
    for (int j = 0; j < 2; ++j) bv[j] = B8[(wn * 2 + j) * 64 + lane];
    #pragma unroll
    for (int i = 0; i < 4; ++i)
      #pragma unroll
      for (int j = 0; j < 2; ++j)
        acc[i][j] = __builtin_amdgcn_mfma_f32_16x16x32_bf16(av[i], bv[j], acc[i][j], 0, 0, 0);
  }
  // epilogue: per 64-row half, stage f16 tile in LDS (stride 72), coalesced stores
  const int r0 = (lane >> 4) * 4, c0 = lane & 15;   // C/D: col=lane&15, row=(lane>>4)*4+reg
  const int row = tid >> 2, q = tid & 3;
  #pragma unroll
  for (int h = 0; h < 2; ++h){
    __syncthreads();
    if (wm == h){
      #pragma unroll
      for (int i = 0; i < 4; ++i){
        #pragma unroll
        for (int j = 0; j < 2; ++j){
          int col = wn * 32 + j * 16 + c0;
          #pragma unroll
          for (int r = 0; r < 4; ++r)
            lds[(i * 16 + r0 + r) * 72 + col] = f2h(acc[i][j][r]);
        }
      }
    }
    __syncthreads();
    int m = tM * 128 + h * 64 + row;
    if (m < M_ROWS){
      const u16* src = lds + row * 72 + q * 16;
      u16* dst = T + (size_t)m * TROW + tn * 64 + q * 16;
      *(uint4*)(dst)     = *(const uint4*)(src);
      *(uint4*)(dst + 8) = *(const uint4*)(src + 8);
    }
  }
}

// ---------------- K3: per-title encoder (512 thr, MLP-staged gather) --------------
__global__ __launch_bounds__(512, 4) void encode_k(
    const int* __restrict__ cand, const int* __restrict__ clk,
    const u16* __restrict__ T,
    const float* __restrict__ b1, const float* __restrict__ b2, const float* __restrict__ b3,
    const float* __restrict__ lng, const float* __restrict__ lnb,
    const float* __restrict__ ql, const float* __restrict__ qw,
    float* __restrict__ rc, float* __restrict__ rh){
  __shared__ __align__(16) u16 ybuf[90][YCOL];   // summed f16 y (27.4 KB)
  __shared__ float tl[32];                        // logits, then normalized ww
  __shared__ float pbuf[8][YCOL];
  __shared__ u32 wordoff[32];
  const int t = blockIdx.x;
  const int tid = threadIdx.x, wave = tid >> 6, lane = tid & 63;
  const int* wp; float* outp;
  if (t < 320){ wp = cand + t * 30;                outp = rc + t * 150; }
  else        { wp = clk + (size_t)(t - 320) * 30; outp = rh + (size_t)(t - 320) * 150; }
  if (tid < 30) wordoff[tid] = (u32)wp[tid] * (u32)TROW;
  __syncthreads();
  const float invs = 0.057735026918962576f;  // 1/sqrt(300)
  const int f0 = lane, f1 = lane + 64, f2 = lane + 128;
  const bool has2 = (f2 < 150);

  // ---- phase 0: gather with 12 loads in flight (T14 issue-early / combine-late).
  uint4 rv[12]; bool vm[12]; int pA[4], fgA[4]; bool ivA[4];
  #pragma unroll
  for (int it = 0; it < 4; ++it){
    const int item = tid + it * 512;
    const bool iv = item < 1710;
    const int p = item / 19, fg = item - p * 19;    // p = l*3+br
    pA[it] = p; fgA[it] = fg; ivA[it] = iv;
    const int l = p / 3, br = p - l * 3, dil = br + 1;
    #pragma unroll
    for (int tap = 0; tap < 3; ++tap){
      const int ls = l + (tap - 1) * dil;
      const int lsc = ls < 0 ? 0 : (ls > 29 ? 29 : ls);
      vm[it * 3 + tap] = iv && (ls >= 0) && (ls < 30);
      rv[it * 3 + tap] = *(const uint4*)(T + wordoff[lsc] + br * 456 + tap * SEG + fg * 8);
    }
  }
  #pragma unroll
  for (int it = 0; it < 4; ++it){
    if (ivA[it]){
      union { uint4 q; h2 h[4]; } s, va, vb, vc;
      const uint4 z4 = (uint4){0u, 0u, 0u, 0u};
      va.q = vm[it * 3]     ? rv[it * 3]     : z4;
      vb.q = vm[it * 3 + 1] ? rv[it * 3 + 1] : z4;
      vc.q = vm[it * 3 + 2] ? rv[it * 3 + 2] : z4;
      #pragma unroll
      for (int i = 0; i < 4; ++i) s.h[i] = va.h[i] + vb.h[i] + vc.h[i];   // v_pk_add_f16
      *(uint4*)&ybuf[pA[it]][fgA[it] * 8] = s.q;
    }
  }

  // preload per-lane params (uniform across words)
  float qlv0 = ql[f0], qlv1 = ql[f1], qlv2 = has2 ? ql[f2] : 0.f;
  float qwv0 = qw[f0], qwv1 = qw[f1], qwv2 = has2 ? qw[f2] : 0.f;
  float lg0 = lng[f0], lg1 = lng[f1], lg2 = has2 ? lng[f2] : 0.f;
  float lb0 = lnb[f0], lb1 = lnb[f1], lb2 = has2 ? lnb[f2] : 0.f;
  float bs[3][3];
  {
    const float* bl[3] = {b1, b2, b3};
    #pragma unroll
    for (int br = 0; br < 3; ++br){
      bs[br][0] = bl[br][f0]; bs[br][1] = bl[br][f1]; bs[br][2] = has2 ? bl[br][f2] : 0.f;
    }
  }
  __syncthreads();

  // ---- phase 1: word-major LN + level-attn (static 4-iter unroll, asm-DPP) ----
  float at0[4], at1[4], at2[4];
  #pragma unroll
  for (int q = 0; q < 4; ++q){
    const int l = wave + q * 8;
    at0[q] = 0.f; at1[q] = 0.f; at2[q] = 0.f;
    if (l < 30){
      float dr[3][3]; float lvl[3];
      #pragma unroll
      for (int br = 0; br < 3; ++br){
        int p = l * 3 + br;
        float y0 = h2f(ybuf[p][f0]) + bs[br][0];
        float y1 = h2f(ybuf[p][f1]) + bs[br][1];
        float y2 = has2 ? (h2f(ybuf[p][f2]) + bs[br][2]) : 0.f;
        float s  = y0 + y1 + y2;
        float ss = y0 * y0 + y1 * y1 + y2 * y2;
        float st = wsum63(s), sst = wsum63(ss);
        float mean = rdl63(st) * (1.f / 150.f);
        float var  = rdl63(sst) * (1.f / 150.f) - mean * mean;
        float rstd = rsqrtf(var + 1e-5f);
        float d0 = fmaxf((y0 - mean) * rstd * lg0 + lb0, 0.f);
        float d1 = fmaxf((y1 - mean) * rstd * lg1 + lb1, 0.f);
        float d2 = has2 ? fmaxf((y2 - mean) * rstd * lg2 + lb2, 0.f) : 0.f;
        dr[br][0] = d0; dr[br][1] = d1; dr[br][2] = d2;
        float dot = qlv0 * d0 + qlv1 * d1 + qlv2 * d2;
        lvl[br] = rdl63(wsum63(dot)) * invs;
      }
      // wave-local level softmax
      float mx = fmaxf(lvl[0], fmaxf(lvl[1], lvl[2]));
      float e0 = __expf(lvl[0] - mx), e1 = __expf(lvl[1] - mx), e2 = __expf(lvl[2] - mx);
      float inv = 1.f / (e0 + e1 + e2);
      float w0 = e0 * inv, w1v = e1 * inv, w2v = e2 * inv;
      float a0 = w0 * dr[0][0] + w1v * dr[1][0] + w2v * dr[2][0];
      float a1 = w0 * dr[0][1] + w1v * dr[1][1] + w2v * dr[2][1];
      float a2 = w0 * dr[0][2] + w1v * dr[1][2] + w2v * dr[2][2];
      float dot = qwv0 * a0 + qwv1 * a1 + qwv2 * a2;
      float tw = wsum63(dot);
      if (lane == 63) tl[l] = tw * invs;
      at0[q] = a0; at1[q] = a1; at2[q] = a2;
    }
  }
  __syncthreads();

  // ---- phase 2a: word softmax ONCE (wave 0), normalized weights -> tl ----
  if (wave == 0){
    float v = (lane < 30) ? tl[lane] : -1e30f;
    float mx = rdl63(wmax63(v));
    float e = (lane < 30) ? __expf(v - mx) : 0.f;
    float den = rdl63(wsum63(e));
    if (lane < 30) tl[lane] = e / den;
  }
  __syncthreads();

  // ---- phase 2b: weighted combine + per-wave partials (static unroll) ----
  float p0 = 0.f, p1 = 0.f, p2 = 0.f;
  #pragma unroll
  for (int q = 0; q < 4; ++q){
    const int l = wave + q * 8;
    if (l < 30){
      float wwv = tl[l];
      p0 += wwv * at0[q]; p1 += wwv * at1[q]; p2 += wwv * at2[q];
    }
  }
  pbuf[wave][lane] = p0;
  pbuf[wave][lane + 64] = p1;
  if (has2) pbuf[wave][lane + 128] = p2;
  __syncthreads();
  if (tid < 150){
    float acc = 0.f;
    #pragma unroll
    for (int w = 0; w < 8; ++w) acc += pbuf[w][tid];
    outp[tid] = acc;
  }
}

// ---------------- K4: scores -> logits -> log_softmax (LDS-staged) ----------------
__global__ __launch_bounds__(256) void final_k(const float* __restrict__ rc, const float* __restrict__ rh,
                                               const float* __restrict__ lw, const float* __restrict__ lb,
                                               float* __restrict__ out){
  __shared__ float Cl[750];
  __shared__ float Hl[7500];
  __shared__ float sc[5][52];
  __shared__ float lg[5];
  const int b = blockIdx.x, tid = threadIdx.x;
  const float* C = rc + b * 750;
  const float* H = rh + (size_t)b * 7500;
  for (int i = tid; i < 750; i += 256) Cl[i] = C[i];
  for (int i = tid; i < 7500; i += 256) Hl[i] = H[i];
  __syncthreads();
  if (tid < 250){
    int c = tid / 50, h = tid % 50;
    float s = 0.f;
    #pragma unroll 10
    for (int k = 0; k < 150; ++k) s += Cl[c * 150 + k] * Hl[h * 150 + k];
    sc[c][h] = s;
  }
  __syncthreads();
  if (tid < 5){
    float s = lb[0];
    for (int h = 0; h < 50; ++h) s += sc[tid][h] * lw[h];
    lg[tid] = s;
  }
  __syncthreads();
  if (tid < 5){
    float mx = fmaxf(fmaxf(fmaxf(lg[0], lg[1]), fmaxf(lg[2], lg[3])), lg[4]);
    float den = 0.f;
    for (int c = 0; c < 5; ++c) den += expf(lg[c] - mx);
    out[b * 5 + tid] = lg[tid] - mx - logf(den);
  }
}

extern "C" void kernel_launch(void* const* d_in, const int* in_sizes, int n_in,
                              void* d_out, int out_size, void* d_ws, size_t ws_size,
                              hipStream_t stream){
  const int*   cand = (const int*)d_in[0];
  const int*   clk  = (const int*)d_in[1];
  const float* emb  = (const float*)d_in[2];
  const float* w1   = (const float*)d_in[3];
  const float* b1   = (const float*)d_in[4];
  const float* w2   = (const float*)d_in[5];
  const float* b2   = (const float*)d_in[6];
  const float* w3   = (const float*)d_in[7];
  const float* b3   = (const float*)d_in[8];
  const float* lng  = (const float*)d_in[9];
  const float* lnb  = (const float*)d_in[10];
  const float* ql   = (const float*)d_in[11];
  const float* qw   = (const float*)d_in[12];
  const float* lw   = (const float*)d_in[13];
  const float* lb   = (const float*)d_in[14];
  float* out = (float*)d_out;

  char* ws = (char*)d_ws;
  const size_t szA = (size_t)M_TILES * KT * 16384;  // 32,112,640 B
  const size_t szB = (size_t)12 * KT * 8192;        //     983,040 B
  const size_t szT = (size_t)M_ROWS * TROW * 2;     // 140,800,000 B
  u16*   A  = (u16*)ws;
  u16*   B  = (u16*)(ws + szA);
  u16*   T  = (u16*)(ws + szA + szB);
  float* rc = (float*)(ws + szA + szB + szT);
  float* rh = rc + 320 * 150;

  build_AB<<<NBLKA + NBLKB, 256, 0, stream>>>(emb, w1, w2, w3, A, B);
  gemm_k<<<dim3(392 * N_TILES64), 256, 0, stream>>>(A, B, T);
  encode_k<<<3520, 512, 0, stream>>>(cand, clk, T, b1, b2, b3, lng, lnb, ql, qw, rc, rh);
  final_k<<<64, 256, 0, stream>>>(rc, rh, lw, lb, out);
}